// Round 2
// baseline (2401.268 us; speedup 1.0000x reference)
//
#include <hip/hip_runtime.h>
#include <hip/hip_bf16.h>

#define B_   4
#define C_   256
#define NTOK 16384          // 128*128
#define M_   (B_*NTOK)

__device__ __forceinline__ float bf2f(unsigned us) { return __uint_as_float(us << 16); }
__device__ __forceinline__ float gelu_exact(float x) {
    return 0.5f * x * (1.f + erff(x * 0.70710678118654752f));
}

// ---------------------------------------------------------------------------
// Unified GEMM: out[M,N] = act(LN?(X)[M,K] @ W(+batch)[K,N] + bias) + res
// 128x128 tile, 8x8/thread. XT/OT: float or bf16. ACT: 0 none, 1 gelu.
// LN_A: apply per-row LN to X during staging using stats(mean,rstd)+lnw/lnb.
// BATCHED_W: W += (blockIdx.y>>7)*K*N  (128 row-tiles per batch).
// ---------------------------------------------------------------------------
template<typename XT, typename OT, int ACT, bool HAS_BIAS, bool HAS_RES, bool LN_A, bool BATCHED_W>
__launch_bounds__(256)
__global__ void gemm128(const XT* __restrict__ X, const float* __restrict__ W,
                        const float* __restrict__ bias, const float* __restrict__ res,
                        OT* __restrict__ out, const float2* __restrict__ stats,
                        const float* __restrict__ lnw, const float* __restrict__ lnb,
                        int K, int N) {
    __shared__ float As[16][128];
    __shared__ float Bs[16][128];
    const int tid = threadIdx.x;
    const int bm = blockIdx.y * 128, bn = blockIdx.x * 128;
    const float* Wb = BATCHED_W ? (W + (size_t)(blockIdx.y >> 7) * K * N) : W;
    const int tx = tid & 15, ty = tid >> 4;
    float acc[8][8];
#pragma unroll
    for (int i = 0; i < 8; i++)
#pragma unroll
        for (int j = 0; j < 8; j++) acc[i][j] = 0.f;

    const int arow = tid >> 1, akb = (tid & 1) * 8;   // A: 8 contiguous k / thread
    const int brow = tid >> 5, bcol = (tid & 31) * 4; // B: 2 float4 rows / thread
    float2 st = {0.f, 0.f};
    if constexpr (LN_A) st = stats[bm + arow];

    for (int k0 = 0; k0 < K; k0 += 16) {
        if constexpr (sizeof(XT) == 4) {
            const float* ap = (const float*)X + (size_t)(bm + arow) * K + k0 + akb;
            float a[8];
            *(float4*)&a[0] = *(const float4*)ap;
            *(float4*)&a[4] = *(const float4*)(ap + 4);
            if constexpr (LN_A) {
#pragma unroll
                for (int j = 0; j < 8; j++)
                    a[j] = (a[j] - st.x) * st.y * lnw[k0 + akb + j] + lnb[k0 + akb + j];
            }
#pragma unroll
            for (int j = 0; j < 8; j++) As[akb + j][arow] = a[j];
        } else {
            const __hip_bfloat16* ap = (const __hip_bfloat16*)X + (size_t)(bm + arow) * K + k0 + akb;
            uint4 u = *(const uint4*)ap;
            As[akb + 0][arow] = bf2f(u.x & 0xffffu); As[akb + 1][arow] = bf2f(u.x >> 16);
            As[akb + 2][arow] = bf2f(u.y & 0xffffu); As[akb + 3][arow] = bf2f(u.y >> 16);
            As[akb + 4][arow] = bf2f(u.z & 0xffffu); As[akb + 5][arow] = bf2f(u.z >> 16);
            As[akb + 6][arow] = bf2f(u.w & 0xffffu); As[akb + 7][arow] = bf2f(u.w >> 16);
        }
        *(float4*)&Bs[brow][bcol]     = *(const float4*)(Wb + (size_t)(k0 + brow) * N + bn + bcol);
        *(float4*)&Bs[brow + 8][bcol] = *(const float4*)(Wb + (size_t)(k0 + brow + 8) * N + bn + bcol);
        __syncthreads();
#pragma unroll
        for (int kk = 0; kk < 16; kk++) {
            float a[8], b[8];
            *(float4*)&a[0] = *(const float4*)&As[kk][ty * 8];
            *(float4*)&a[4] = *(const float4*)&As[kk][ty * 8 + 4];
            *(float4*)&b[0] = *(const float4*)&Bs[kk][tx * 8];
            *(float4*)&b[4] = *(const float4*)&Bs[kk][tx * 8 + 4];
#pragma unroll
            for (int i = 0; i < 8; i++)
#pragma unroll
                for (int j = 0; j < 8; j++) acc[i][j] += a[i] * b[j];
        }
        __syncthreads();
    }
#pragma unroll
    for (int i = 0; i < 8; i++) {
        const size_t r = (size_t)(bm + ty * 8 + i);
#pragma unroll
        for (int j = 0; j < 8; j++) {
            const int cn = bn + tx * 8 + j;
            float v = acc[i][j];
            if constexpr (HAS_BIAS) v += bias[cn];
            if constexpr (ACT == 1) v = gelu_exact(v);
            if constexpr (HAS_RES)  v += res[r * N + cn];
            if constexpr (sizeof(OT) == 4) ((float*)out)[r * N + cn] = v;
            else ((__hip_bfloat16*)out)[r * N + cn] = __float2bfloat16(v);
        }
    }
}

// ---------------------------------------------------------------------------
// Depthwise 3x3 conv PE (+residual). Optional per-token LN stats (mean,rstd),
// optional channel pooling. Block: 256 threads = channels, 16 tokens.
// ---------------------------------------------------------------------------
template<bool DO_STATS, bool DO_POOL>
__launch_bounds__(256)
__global__ void dwconv_pe_kernel(const float* __restrict__ in, const float* __restrict__ wconv,
                                 const float* __restrict__ bconv, float* __restrict__ out,
                                 float2* __restrict__ stats, float* __restrict__ pooled,
                                 int pool_off) {
    const int b = blockIdx.y;
    const int n0 = blockIdx.x * 16;
    const int h = n0 >> 7;
    const int w0 = n0 & 127;
    const int c = threadIdx.x;
    float wr[9];
#pragma unroll
    for (int i = 0; i < 9; i++) wr[i] = wconv[c * 9 + i];
    const float bb = bconv[c];
    const float* base = in  + (size_t)b * NTOK * C_ + c;
    float* obase      = out + (size_t)b * NTOK * C_ + c;
    float pacc = 0.f;
    __shared__ float red[8];
    const int lane = c & 63, wv = c >> 6;
    for (int t = 0; t < 16; t++) {
        const int w = w0 + t;
        float val = bb;
#pragma unroll
        for (int dh = -1; dh <= 1; dh++) {
            const int h2 = h + dh;
            if ((unsigned)h2 < 128u) {
#pragma unroll
                for (int dw = -1; dw <= 1; dw++) {
                    const int w2 = w + dw;
                    if ((unsigned)w2 < 128u)
                        val += wr[(dh + 1) * 3 + (dw + 1)] * base[((size_t)(h2 << 7) + w2) * C_];
                }
            }
        }
        const size_t oidx = ((size_t)(h << 7) + w) * C_;
        const float o = base[oidx] + val;
        obase[oidx] = o;
        if constexpr (DO_POOL) pacc += o;
        if constexpr (DO_STATS) {
            float sx = o, sy = o * o;
#pragma unroll
            for (int off = 32; off; off >>= 1) { sx += __shfl_xor(sx, off); sy += __shfl_xor(sy, off); }
            if (lane == 0) { red[wv * 2] = sx; red[wv * 2 + 1] = sy; }
            __syncthreads();
            const float tsx = red[0] + red[2] + red[4] + red[6];
            const float tsy = red[1] + red[3] + red[5] + red[7];
            __syncthreads();
            if (c == 0) {
                const float mean = tsx * (1.f / 256.f);
                const float var  = tsy * (1.f / 256.f) - mean * mean;
                stats[(size_t)b * NTOK + n0 + t] = make_float2(mean, rsqrtf(var + 1e-5f));
            }
        }
    }
    if constexpr (DO_POOL) atomicAdd(&pooled[b * 512 + pool_off + c], pacc);
}

// ---------------------------------------------------------------------------
// Gram: G[b] += chunk of Y^T Y (Y optionally LN'd on the fly).
// grid (16 tiles of 64x64, 8 k-chunks, B), 256 thr, 4x4 acc.
// ---------------------------------------------------------------------------
template<bool LNA>
__launch_bounds__(256)
__global__ void gram_kernel(const float* __restrict__ Y, const float2* __restrict__ stats,
                            const float* __restrict__ lnw, const float* __restrict__ lnb,
                            float* __restrict__ G) {
    const int b = blockIdx.z;
    const int i0 = (blockIdx.x >> 2) * 64, j0 = (blockIdx.x & 3) * 64;
    const int n0 = blockIdx.y * (NTOK / 8);
    __shared__ float Yi[16][64];
    __shared__ float Yj[16][64];
    const int tid = threadIdx.x;
    const int sr = tid >> 4, sc = (tid & 15) * 4;
    const int tx = tid & 15, ty = tid >> 4;
    float acc[4][4];
#pragma unroll
    for (int i = 0; i < 4; i++)
#pragma unroll
        for (int j = 0; j < 4; j++) acc[i][j] = 0.f;
    const float* Yb = Y + (size_t)b * NTOK * C_;
    for (int nn = 0; nn < NTOK / 8; nn += 16) {
        const int row = n0 + nn + sr;
        float4 ai = *(const float4*)&Yb[(size_t)row * C_ + i0 + sc];
        float4 aj = *(const float4*)&Yb[(size_t)row * C_ + j0 + sc];
        if constexpr (LNA) {
            const float2 st = stats[(size_t)b * NTOK + row];
            ai.x = (ai.x - st.x) * st.y * lnw[i0 + sc + 0] + lnb[i0 + sc + 0];
            ai.y = (ai.y - st.x) * st.y * lnw[i0 + sc + 1] + lnb[i0 + sc + 1];
            ai.z = (ai.z - st.x) * st.y * lnw[i0 + sc + 2] + lnb[i0 + sc + 2];
            ai.w = (ai.w - st.x) * st.y * lnw[i0 + sc + 3] + lnb[i0 + sc + 3];
            aj.x = (aj.x - st.x) * st.y * lnw[j0 + sc + 0] + lnb[j0 + sc + 0];
            aj.y = (aj.y - st.x) * st.y * lnw[j0 + sc + 1] + lnb[j0 + sc + 1];
            aj.z = (aj.z - st.x) * st.y * lnw[j0 + sc + 2] + lnb[j0 + sc + 2];
            aj.w = (aj.w - st.x) * st.y * lnw[j0 + sc + 3] + lnb[j0 + sc + 3];
        }
        *(float4*)&Yi[sr][sc] = ai;
        *(float4*)&Yj[sr][sc] = aj;
        __syncthreads();
#pragma unroll
        for (int n = 0; n < 16; n++) {
            float a[4], c4[4];
            *(float4*)&a[0]  = *(const float4*)&Yi[n][ty * 4];
            *(float4*)&c4[0] = *(const float4*)&Yj[n][tx * 4];
#pragma unroll
            for (int i = 0; i < 4; i++)
#pragma unroll
                for (int j = 0; j < 4; j++) acc[i][j] += a[i] * c4[j];
        }
        __syncthreads();
    }
#pragma unroll
    for (int i = 0; i < 4; i++)
#pragma unroll
        for (int j = 0; j < 4; j++)
            atomicAdd(&G[(size_t)b * 65536 + (size_t)(i0 + ty * 4 + i) * 256 + j0 + tx * 4 + j],
                      acc[i][j]);
}

// ---------------------------------------------------------------------------
// S[b,hh,d,e] = scale * (Wk_hh^T @ G_b @ Wv_hh)[d,e].  grid 32 = (b*8+hh).
// ---------------------------------------------------------------------------
__launch_bounds__(256)
__global__ void sfromg_kernel(const float* __restrict__ G, const float* __restrict__ kv_w,
                              float* __restrict__ SM) {
    const int b = blockIdx.x >> 3, hh = blockIdx.x & 7;
    const int tid = threadIdx.x;
    __shared__ float Tl[256][33];
    __shared__ float Wvl[32][33];
    float acc[32];
#pragma unroll
    for (int e = 0; e < 32; e++) acc[e] = 0.f;
    const float* Gb = G + (size_t)b * 65536;
    for (int c0 = 0; c0 < 256; c0 += 32) {
        // stage G rows x 32 cols into Tl (reused as G-chunk)
#pragma unroll
        for (int q = 0; q < 8; q++) {
            const int idx = q * 256 + tid;
            const int r = idx >> 3, c4 = (idx & 7) * 4;
            *(float4*)&Tl[r][c4] = *(const float4*)&Gb[(size_t)r * 256 + c0 + c4];
        }
        {
            const int cc = tid >> 3, e4 = (tid & 7) * 4;
            *(float4*)&Wvl[cc][e4] = *(const float4*)&kv_w[(size_t)(c0 + cc) * 512 + 256 + hh * 32 + e4];
        }
        __syncthreads();
#pragma unroll 4
        for (int cc = 0; cc < 32; cc++) {
            const float g = Tl[tid][cc];
#pragma unroll
            for (int e = 0; e < 32; e++) acc[e] += g * Wvl[cc][e];
        }
        __syncthreads();
    }
    // write T = G @ Wv_hh into Tl, then S = Wk_hh^T @ T
#pragma unroll
    for (int e = 0; e < 32; e++) Tl[tid][e] = acc[e];
    __syncthreads();
    const int e = tid & 31, d0 = (tid >> 5) * 4;
    float s[4] = {0.f, 0.f, 0.f, 0.f};
    for (int r = 0; r < 256; r++) {
        const float t = Tl[r][e];
#pragma unroll
        for (int i = 0; i < 4; i++) s[i] += kv_w[(size_t)r * 512 + hh * 32 + d0 + i] * t;
    }
#pragma unroll
    for (int i = 0; i < 4; i++)
        SM[((size_t)(b * 8 + hh) * 32 + d0 + i) * 32 + e] = s[i] * 0.17677669529663687f;
}

__launch_bounds__(256)
__global__ void softmax32_kernel(float* __restrict__ Sm) {
    const int row = blockIdx.x * 8 + (threadIdx.x >> 5);
    const int e = threadIdx.x & 31;
    float v = Sm[row * 32 + e];
    float m = v;
#pragma unroll
    for (int off = 16; off; off >>= 1) m = fmaxf(m, __shfl_xor(m, off, 32));
    const float ex = expf(v - m);
    float s = ex;
#pragma unroll
    for (int off = 16; off; off >>= 1) s += __shfl_xor(s, off, 32);
    Sm[row * 32 + e] = ex / s;
}

// ---------------------------------------------------------------------------
// T1[b][i, hh*32+d] = sum_e q_w[i, hh*32+e] * A[b,hh,d,e].  grid 32 = (b*8+hh).
// ---------------------------------------------------------------------------
__launch_bounds__(256)
__global__ void weff1_kernel(const float* __restrict__ q_w, const float* __restrict__ SM,
                             float* __restrict__ T1) {
    const int b = blockIdx.x >> 3, hh = blockIdx.x & 7;
    const int tid = threadIdx.x;
    __shared__ float A[32][33];
    {
        const int d = tid >> 3, e4 = (tid & 7) * 4;
        *(float4*)&A[d][e4] = *(const float4*)&SM[((size_t)(b * 8 + hh) * 32 + d) * 32 + e4];
    }
    __syncthreads();
    float qr[32];
#pragma unroll
    for (int e4 = 0; e4 < 8; e4++)
        *(float4*)&qr[e4 * 4] = *(const float4*)&q_w[(size_t)tid * 256 + hh * 32 + e4 * 4];
    float o[32];
#pragma unroll 4
    for (int d = 0; d < 32; d++) {
        float s = 0.f;
#pragma unroll
        for (int e = 0; e < 32; e++) s += qr[e] * A[d][e];
        o[d] = s;
    }
#pragma unroll
    for (int d4 = 0; d4 < 8; d4++)
        *(float4*)&T1[(size_t)b * 65536 + (size_t)tid * 256 + hh * 32 + d4 * 4] = *(float4*)&o[d4 * 4];
}

// ---------------------------------------------------------------------------
// WT[b] = T1[b] @ proj_w.  grid (4,4,B), 64x64 tile, 4x4/thread.
// ---------------------------------------------------------------------------
__launch_bounds__(256)
__global__ void weff2_kernel(const float* __restrict__ T1, const float* __restrict__ pw,
                             float* __restrict__ WT) {
    const int b = blockIdx.z;
    const int i0 = blockIdx.y * 64, j0 = blockIdx.x * 64;
    __shared__ float As[16][64];
    __shared__ float Bs[16][64];
    const int tid = threadIdx.x;
    const int tx = tid & 15, ty = tid >> 4;
    float acc[4][4];
#pragma unroll
    for (int i = 0; i < 4; i++)
#pragma unroll
        for (int j = 0; j < 4; j++) acc[i][j] = 0.f;
    const int ar = tid >> 2, ak4 = (tid & 3) * 4;    // A: row i0+ar, k-chunk
    const int bk = tid >> 4, bj4 = (tid & 15) * 4;   // B: row k0+bk
    for (int k0 = 0; k0 < 256; k0 += 16) {
        float4 av = *(const float4*)&T1[(size_t)b * 65536 + (size_t)(i0 + ar) * 256 + k0 + ak4];
        As[ak4 + 0][ar] = av.x; As[ak4 + 1][ar] = av.y;
        As[ak4 + 2][ar] = av.z; As[ak4 + 3][ar] = av.w;
        *(float4*)&Bs[bk][bj4] = *(const float4*)&pw[(size_t)(k0 + bk) * 256 + j0 + bj4];
        __syncthreads();
#pragma unroll
        for (int kk = 0; kk < 16; kk++) {
            float a[4], c4[4];
            *(float4*)&a[0]  = *(const float4*)&As[kk][ty * 4];
            *(float4*)&c4[0] = *(const float4*)&Bs[kk][tx * 4];
#pragma unroll
            for (int i = 0; i < 4; i++)
#pragma unroll
                for (int j = 0; j < 4; j++) acc[i][j] += a[i] * c4[j];
        }
        __syncthreads();
    }
#pragma unroll
    for (int i = 0; i < 4; i++)
#pragma unroll
        for (int j = 0; j < 4; j++)
            WT[(size_t)b * 65536 + (size_t)(i0 + ty * 4 + i) * 256 + j0 + tx * 4 + j] = acc[i][j];
}

__launch_bounds__(256)
__global__ void add_kernel(float* __restrict__ a, const float* __restrict__ b, int n4) {
    const int i = blockIdx.x * 256 + threadIdx.x;
    if (i < n4) {
        float4 x = ((const float4*)a)[i];
        const float4 y = ((const float4*)b)[i];
        x.x += y.x; x.y += y.y; x.z += y.z; x.w += y.w;
        ((float4*)a)[i] = x;
    }
}

// channel-interaction tiny MLP: g = sigmoid(gelu(pooled/N @ w1 + b1) @ w2 + b2)
__launch_bounds__(256)
__global__ void ci_kernel(const float* __restrict__ pooled, const float* __restrict__ w1,
                          const float* __restrict__ b1, const float* __restrict__ w2,
                          const float* __restrict__ b2, float* __restrict__ g) {
    const int b = blockIdx.x, t = threadIdx.x;
    __shared__ float pl[512];
    __shared__ float hid[256];
    pl[t]       = pooled[b * 512 + t]       * (1.f / NTOK);
    pl[t + 256] = pooled[b * 512 + 256 + t] * (1.f / NTOK);
    __syncthreads();
    float h = b1[t];
    for (int k = 0; k < 512; k++) h += pl[k] * w1[k * 256 + t];
    hid[t] = gelu_exact(h);
    __syncthreads();
    float g0 = b2[t], g1 = b2[t + 256];
    for (int k = 0; k < 256; k++) {
        const float hv = hid[k];
        g0 += hv * w2[k * 512 + t];
        g1 += hv * w2[k * 512 + 256 + t];
    }
    g[b * 512 + t]       = 1.f / (1.f + expf(-g0));
    g[b * 512 + 256 + t] = 1.f / (1.f + expf(-g1));
}

// ft = s_x*y2 + s_y*x2, store ft + per-token LN stats.
__launch_bounds__(256)
__global__ void fcomb_kernel(const float* __restrict__ g, const float* __restrict__ x2,
                             const float* __restrict__ y2, float* __restrict__ ft,
                             float2* __restrict__ stats) {
    const int b = blockIdx.y;
    const int n0 = blockIdx.x * 16;
    const int c = threadIdx.x;
    const float sx = g[b * 512 + c];         // scales y2
    const float sy = g[b * 512 + 256 + c];   // scales x2
    const size_t base = ((size_t)b * NTOK + n0) * C_ + c;
    __shared__ float red[8];
    const int lane = c & 63, wv = c >> 6;
    for (int t = 0; t < 16; t++) {
        const size_t idx = base + (size_t)t * C_;
        const float f = sx * y2[idx] + sy * x2[idx];
        ft[idx] = f;
        float vx = f, vy = f * f;
#pragma unroll
        for (int off = 32; off; off >>= 1) { vx += __shfl_xor(vx, off); vy += __shfl_xor(vy, off); }
        if (lane == 0) { red[wv * 2] = vx; red[wv * 2 + 1] = vy; }
        __syncthreads();
        const float tsx = red[0] + red[2] + red[4] + red[6];
        const float tsy = red[1] + red[3] + red[5] + red[7];
        __syncthreads();
        if (c == 0) {
            const float mean = tsx * (1.f / 256.f);
            const float var  = tsy * (1.f / 256.f) - mean * mean;
            stats[(size_t)b * NTOK + n0 + t] = make_float2(mean, rsqrtf(var + 1e-5f));
        }
    }
}

// out[b][c][n] = in[b][n][c]
__launch_bounds__(256)
__global__ void transpose_kernel(const float* __restrict__ in, float* __restrict__ out) {
    __shared__ float tile[32][33];
    const int b = blockIdx.z;
    const int n0 = blockIdx.x * 32, c0 = blockIdx.y * 32;
    const int tx = threadIdx.x & 31, ty = threadIdx.x >> 5;
    const float* ip = in + (size_t)b * NTOK * C_;
#pragma unroll
    for (int i = 0; i < 32; i += 8)
        tile[ty + i][tx] = ip[(size_t)(n0 + ty + i) * C_ + c0 + tx];
    __syncthreads();
    float* op = out + (size_t)b * C_ * NTOK;
#pragma unroll
    for (int i = 0; i < 32; i += 8)
        op[(size_t)(c0 + ty + i) * NTOK + n0 + tx] = tile[tx][ty + i];
}

// ---------------------------------------------------------------------------
extern "C" void kernel_launch(void* const* d_in, const int* in_sizes, int n_in,
                              void* d_out, int out_size, void* d_ws, size_t ws_size,
                              hipStream_t stream) {
    const float* x        = (const float*)d_in[0];
    const float* y        = (const float*)d_in[1];
    const float* cpex0_w  = (const float*)d_in[2];
    const float* cpex0_b  = (const float*)d_in[3];
    const float* cpey0_w  = (const float*)d_in[4];
    const float* cpey0_b  = (const float*)d_in[5];
    const float* cpex1_w  = (const float*)d_in[6];
    const float* cpex1_b  = (const float*)d_in[7];
    const float* cpey1_w  = (const float*)d_in[8];
    const float* cpey1_b  = (const float*)d_in[9];
    const float* ln1x_w   = (const float*)d_in[10];
    const float* ln1x_b   = (const float*)d_in[11];
    const float* ln1y_w   = (const float*)d_in[12];
    const float* ln1y_b   = (const float*)d_in[13];
    const float* ln2_w    = (const float*)d_in[14];
    const float* ln2_b    = (const float*)d_in[15];
    const float* attnx_kv = (const float*)d_in[16];
    const float* attnx_q  = (const float*)d_in[17];
    const float* attnx_pw = (const float*)d_in[18];
    const float* attnx_pb = (const float*)d_in[19];
    const float* attny_kv = (const float*)d_in[20];
    const float* attny_q  = (const float*)d_in[21];
    const float* attny_pw = (const float*)d_in[22];
    const float* attny_pb = (const float*)d_in[23];
    const float* ci_w1    = (const float*)d_in[24];
    const float* ci_b1    = (const float*)d_in[25];
    const float* ci_w2    = (const float*)d_in[26];
    const float* ci_b2    = (const float*)d_in[27];
    const float* fc1_w    = (const float*)d_in[28];
    const float* fc1_b    = (const float*)d_in[29];
    const float* fc2_w    = (const float*)d_in[30];
    const float* fc2_b    = (const float*)d_in[31];
    (void)in_sizes; (void)n_in; (void)out_size; (void)ws_size;

    float* ws = (float*)d_ws;
    // small scratch first (low addresses), big slots after
    float2* STX  = (float2*)(ws + 0);         // 65536 float2
    float2* STY  = (float2*)(ws + 131072);
    float2* STF  = (float2*)(ws + 262144);
    float*  GRAM = ws + 393216;               // 262144 floats (1 MB)
    float*  SM   = ws + 655360;               // 32768
    float*  T1   = ws + 688128;               // 262144
    float*  WT   = ws + 950272;               // 262144
    float*  PL   = ws + 1212416;              // 2048
    float*  GT   = ws + 1214464;              // 2048
    const size_t S = (size_t)M_ * C_;         // 16,777,216 floats (64 MB)
    float* A = ws + 2097152;                  // slots: total ws need = 8MB + 192MB
    float* Bs = A + S;
    float* Cs = Bs + S;
    float* OUT = (float*)d_out;               // doubles as y_new slot

    const dim3 blk(256);
    const dim3 g_dw(NTOK / 16, B_);
    const dim3 g_gram(16, 8, B_);
    const dim3 g_w2(4, 4, B_);

    // 1) dwconv PE #1 + LN stats
    dwconv_pe_kernel<true, false><<<g_dw, blk, 0, stream>>>(x, cpex0_w, cpex0_b, A, STX, nullptr, 0);
    dwconv_pe_kernel<true, false><<<g_dw, blk, 0, stream>>>(y, cpey0_w, cpey0_b, Bs, STY, nullptr, 0);

    // 2) XCA_x in weight space: S = Wk^T (cury^T cury) Wv ; W_total = q_w M proj_w
    hipMemsetAsync(GRAM, 0, 262144 * sizeof(float), stream);
    gram_kernel<true><<<g_gram, blk, 0, stream>>>(Bs, STY, ln1y_w, ln1y_b, GRAM);
    sfromg_kernel<<<dim3(32), blk, 0, stream>>>(GRAM, attnx_kv, SM);
    softmax32_kernel<<<dim3(128), blk, 0, stream>>>(SM);
    weff1_kernel<<<dim3(32), blk, 0, stream>>>(attnx_q, SM, T1);
    weff2_kernel<<<g_w2, blk, 0, stream>>>(T1, attnx_pw, WT);
    // curx_attn = LN(x_pe) @ WT[b] + pb  -> Cs
    gemm128<float, float, 0, true, false, true, true><<<dim3(2, 512), blk, 0, stream>>>(
        A, WT, attnx_pb, nullptr, Cs, STX, ln1x_w, ln1x_b, 256, 256);

    // 3) XCA_y: kv from curx_attn (raw), q from LN(y_pe); y_new -> OUT
    hipMemsetAsync(GRAM, 0, 262144 * sizeof(float), stream);
    gram_kernel<false><<<g_gram, blk, 0, stream>>>(Cs, nullptr, nullptr, nullptr, GRAM);
    sfromg_kernel<<<dim3(32), blk, 0, stream>>>(GRAM, attny_kv, SM);
    softmax32_kernel<<<dim3(128), blk, 0, stream>>>(SM);
    weff1_kernel<<<dim3(32), blk, 0, stream>>>(attny_q, SM, T1);
    weff2_kernel<<<g_w2, blk, 0, stream>>>(T1, attny_pw, WT);
    gemm128<float, float, 0, true, true, true, true><<<dim3(2, 512), blk, 0, stream>>>(
        Bs, WT, attny_pb, Bs, OUT, STY, ln1y_w, ln1y_b, 256, 256);

    // 4) x_new = x_pe + curx_attn  (in-place into A)
    add_kernel<<<dim3((unsigned)((S / 4 + 255) / 256)), blk, 0, stream>>>(A, Cs, (int)(S / 4));

    // 5) dwconv PE #2 + pooling
    hipMemsetAsync(PL, 0, 2048 * sizeof(float), stream);
    dwconv_pe_kernel<false, true><<<g_dw, blk, 0, stream>>>(A, cpex1_w, cpex1_b, Cs, nullptr, PL, 0);
    dwconv_pe_kernel<false, true><<<g_dw, blk, 0, stream>>>(OUT, cpey1_w, cpey1_b, Bs, nullptr, PL, 256);

    // 6) gates
    ci_kernel<<<dim3(B_), blk, 0, stream>>>(PL, ci_w1, ci_b1, ci_w2, ci_b2, GT);

    // 7) ft = s_x*y2 + s_y*x2 -> A, + ln2 stats
    fcomb_kernel<<<g_dw, blk, 0, stream>>>(GT, Cs, Bs, A, STF);

    // 8) MLP: hidden bf16 in Bs..Cs (128 MB), out + ft residual -> A
    gemm128<float, __hip_bfloat16, 1, true, false, true, false><<<dim3(8, 512), blk, 0, stream>>>(
        A, fc1_w, fc1_b, nullptr, (__hip_bfloat16*)Bs, STF, ln2_w, ln2_b, 256, 1024);
    gemm128<__hip_bfloat16, float, 0, true, true, false, false><<<dim3(2, 512), blk, 0, stream>>>(
        (const __hip_bfloat16*)Bs, fc2_w, fc2_b, A, A, nullptr, nullptr, nullptr, 1024, 256);

    // 9) (B,N,C) -> (B,C,H,W)
    transpose_kernel<<<dim3(NTOK / 32, C_ / 32, B_), blk, 0, stream>>>(A, OUT);
}

// Round 3
// 1414.768 us; speedup vs baseline: 1.6973x; 1.6973x over previous
//
#include <hip/hip_runtime.h>
#include <hip/hip_bf16.h>

#define B_   4
#define C_   256
#define NTOK 16384          // 128*128
#define M_   (B_*NTOK)

typedef unsigned short u16;
typedef __attribute__((ext_vector_type(8))) short short8;
typedef __attribute__((ext_vector_type(4))) float f32x4;

#if defined(__has_builtin)
# if __has_builtin(__builtin_amdgcn_global_load_lds)
#  define HAVE_GLL 1
# endif
#endif
#ifndef HAVE_GLL
# define HAVE_GLL 0
#endif

__device__ __forceinline__ float gelu_exact(float x) {
    return 0.5f * x * (1.f + erff(x * 0.70710678118654752f));
}
__device__ __forceinline__ u16 f2bf(float f) {
    __hip_bfloat16 h = __float2bfloat16(f);
    return *reinterpret_cast<u16*>(&h);
}

#if HAVE_GLL
__device__ __forceinline__ void gload16(const void* g, void* lds_uniform) {
    __builtin_amdgcn_global_load_lds((const __attribute__((address_space(1))) unsigned int*)g,
                                     (__attribute__((address_space(3))) unsigned int*)lds_uniform,
                                     16, 0, 0);
}
#endif

// ---------------------------------------------------------------------------
// MFMA GEMM: out[M,N] = epi( A[M,K] @ Bt[N,K]^T ).  128x128 tile, BK=64,
// 4 waves of 64x64, 16x16x32 bf16 MFMA. A: bf16 (global_load_lds) or fp32+LN
// (VALU staging). Bt is bf16 row-major [N][ldB] (i.e. B transposed).
// XOR-swizzle on 16B chunks within each 128B LDS row kills frag-read bank
// conflicts while staying global_load_lds-compatible (swizzle the GLOBAL addr).
// z: batch*nsplit+split (split-K with atomic fp32 output for Gram).
// ---------------------------------------------------------------------------
template<bool LN_A, bool HAS_BIAS, int ACT, bool HAS_RES, bool OUT_F32, bool OUT_BF16, bool ATOMIC>
__launch_bounds__(256)
__global__ void gemm_mfma(const u16* __restrict__ Abf, const float* __restrict__ Af,
                          const float2* __restrict__ stats, const float* __restrict__ lnw,
                          const float* __restrict__ lnb,
                          const u16* __restrict__ Bt, const float* __restrict__ bias,
                          const float* __restrict__ res, float* __restrict__ outf,
                          u16* __restrict__ outb,
                          int K, int ldA, int ldB, int N, int nsplit,
                          size_t aBS, size_t bBS, size_t oBS, size_t rBS) {
    __shared__ __align__(16) u16 As[128 * 64];
    __shared__ __align__(16) u16 Bs[128 * 64];
    const int tid = threadIdx.x;
    const int bm = blockIdx.y * 128, bn = blockIdx.x * 128;
    int batch = blockIdx.z, split = 0;
    if (nsplit > 1) { batch = blockIdx.z / nsplit; split = blockIdx.z - batch * nsplit; }
    const int KL = K / nsplit;
    const int kb = split * KL;
    const size_t aoff = (size_t)batch * aBS, boff = (size_t)batch * bBS;
    const size_t ooff = (size_t)batch * oBS, roff = (size_t)batch * rBS;
    const size_t soff = (size_t)batch * NTOK;

    const int lane = tid & 63, wv = tid >> 6;
    const int wm = wv >> 1, wn = wv & 1;
    const int r16 = lane & 15, kg = lane >> 4;

    f32x4 acc[4][4];
#pragma unroll
    for (int i = 0; i < 4; i++)
#pragma unroll
        for (int j = 0; j < 4; j++) acc[i][j] = (f32x4){0.f, 0.f, 0.f, 0.f};

    for (int kk = 0; kk < KL; kk += 64) {
        const int k0 = kb + kk;
        // ---- stage B tile (bf16, [128 n][64 k] with chunk swizzle) ----
#pragma unroll
        for (int it = 0; it < 4; it++) {
            const int chunk = it * 256 + tid;          // 0..1023 (16B units)
            const int row = chunk >> 3, c = chunk & 7;
            const int g = c ^ (row & 7);
            const u16* gp = Bt + boff + (size_t)(bn + row) * ldB + k0 + g * 8;
#if HAVE_GLL
            gload16(gp, (char*)Bs + it * 4096 + wv * 1024);
#else
            *(uint4*)((char*)Bs + chunk * 16) = *(const uint4*)gp;
#endif
        }
        // ---- stage A tile ----
        if constexpr (LN_A) {
#pragma unroll
            for (int q = 0; q < 4; q++) {
                const int chunk = q * 256 + tid;
                const int row = chunk >> 3, c = chunk & 7;
                const int g = c ^ (row & 7);           // slot c holds global chunk g? (store to swizzled slot)
                const float* ap = Af + aoff + (size_t)(bm + row) * ldA + k0 + c * 8;
                const float2 st = stats[soff + bm + row];
                const float4 v0 = *(const float4*)ap;
                const float4 v1 = *(const float4*)(ap + 4);
                const float* w = lnw + k0 + c * 8;
                const float* bb = lnb + k0 + c * 8;
                u16 u[8];
                u[0] = f2bf((v0.x - st.x) * st.y * w[0] + bb[0]);
                u[1] = f2bf((v0.y - st.x) * st.y * w[1] + bb[1]);
                u[2] = f2bf((v0.z - st.x) * st.y * w[2] + bb[2]);
                u[3] = f2bf((v0.w - st.x) * st.y * w[3] + bb[3]);
                u[4] = f2bf((v1.x - st.x) * st.y * w[4] + bb[4]);
                u[5] = f2bf((v1.y - st.x) * st.y * w[5] + bb[5]);
                u[6] = f2bf((v1.z - st.x) * st.y * w[6] + bb[6]);
                u[7] = f2bf((v1.w - st.x) * st.y * w[7] + bb[7]);
                uint4 pk;
                pk.x = (unsigned)u[0] | ((unsigned)u[1] << 16);
                pk.y = (unsigned)u[2] | ((unsigned)u[3] << 16);
                pk.z = (unsigned)u[4] | ((unsigned)u[5] << 16);
                pk.w = (unsigned)u[6] | ((unsigned)u[7] << 16);
                // global chunk c stored at physical slot c^(row&7)
                *(uint4*)&As[row * 64 + g * 8] = pk;
            }
        } else {
#pragma unroll
            for (int it = 0; it < 4; it++) {
                const int chunk = it * 256 + tid;
                const int row = chunk >> 3, c = chunk & 7;
                const int g = c ^ (row & 7);
                const u16* gp = Abf + aoff + (size_t)(bm + row) * ldA + k0 + g * 8;
#if HAVE_GLL
                gload16(gp, (char*)As + it * 4096 + wv * 1024);
#else
                *(uint4*)((char*)As + chunk * 16) = *(const uint4*)gp;
#endif
            }
        }
        __syncthreads();
        // ---- frags + MFMA ----
        short8 af[4][2], bfr[4][2];
#pragma unroll
        for (int t = 0; t < 4; t++) {
#pragma unroll
            for (int kh = 0; kh < 2; kh++) {
                const int lc = kh * 4 + kg;            // logical 16B chunk
                const int ra = wm * 64 + t * 16 + r16;
                const int rb = wn * 64 + t * 16 + r16;
                af[t][kh]  = *(const short8*)&As[ra * 64 + ((lc ^ (ra & 7)) << 3)];
                bfr[t][kh] = *(const short8*)&Bs[rb * 64 + ((lc ^ (rb & 7)) << 3)];
            }
        }
#pragma unroll
        for (int mt = 0; mt < 4; mt++)
#pragma unroll
            for (int nt = 0; nt < 4; nt++)
#pragma unroll
                for (int kh = 0; kh < 2; kh++)
                    acc[mt][nt] = __builtin_amdgcn_mfma_f32_16x16x32_bf16(
                        af[mt][kh], bfr[nt][kh], acc[mt][nt], 0, 0, 0);
        __syncthreads();
    }
    // ---- epilogue: C/D layout col=lane&15, row=(lane>>4)*4+reg ----
#pragma unroll
    for (int mt = 0; mt < 4; mt++) {
        const int gm0 = bm + wm * 64 + mt * 16 + kg * 4;
#pragma unroll
        for (int nt = 0; nt < 4; nt++) {
            const int gn = bn + wn * 64 + nt * 16 + r16;
            float bv = 0.f;
            if constexpr (HAS_BIAS) bv = bias[gn];
#pragma unroll
            for (int r = 0; r < 4; r++) {
                float v = acc[mt][nt][r];
                const size_t oi = (size_t)(gm0 + r) * N + gn;
                if constexpr (ATOMIC) {
                    atomicAdd(&outf[ooff + oi], v);
                } else {
                    v += bv;
                    if constexpr (ACT == 1) v = gelu_exact(v);
                    if constexpr (OUT_BF16) outb[ooff + oi] = f2bf(v);
                    if constexpr (HAS_RES) v += res[roff + oi];
                    if constexpr (OUT_F32) outf[ooff + oi] = v;
                }
            }
        }
    }
}

// ---------------------------------------------------------------------------
// Depthwise 3x3 conv PE (+residual). Optional per-token LN stats, optional
// channel pooling. Block: 256 threads = channels, 16 tokens.
// ---------------------------------------------------------------------------
template<bool DO_STATS, bool DO_POOL>
__launch_bounds__(256)
__global__ void dwconv_pe_kernel(const float* __restrict__ in, const float* __restrict__ wconv,
                                 const float* __restrict__ bconv, float* __restrict__ out,
                                 float2* __restrict__ stats, float* __restrict__ pooled,
                                 int pool_off) {
    const int b = blockIdx.y;
    const int n0 = blockIdx.x * 16;
    const int h = n0 >> 7;
    const int w0 = n0 & 127;
    const int c = threadIdx.x;
    float wr[9];
#pragma unroll
    for (int i = 0; i < 9; i++) wr[i] = wconv[c * 9 + i];
    const float bb = bconv[c];
    const float* base = in  + (size_t)b * NTOK * C_ + c;
    float* obase      = out + (size_t)b * NTOK * C_ + c;
    float pacc = 0.f;
    __shared__ float red[8];
    const int lane = c & 63, wv = c >> 6;
    for (int t = 0; t < 16; t++) {
        const int w = w0 + t;
        float val = bb;
#pragma unroll
        for (int dh = -1; dh <= 1; dh++) {
            const int h2 = h + dh;
            if ((unsigned)h2 < 128u) {
#pragma unroll
                for (int dw = -1; dw <= 1; dw++) {
                    const int w2 = w + dw;
                    if ((unsigned)w2 < 128u)
                        val += wr[(dh + 1) * 3 + (dw + 1)] * base[((size_t)(h2 << 7) + w2) * C_];
                }
            }
        }
        const size_t oidx = ((size_t)(h << 7) + w) * C_;
        const float o = base[oidx] + val;
        obase[oidx] = o;
        if constexpr (DO_POOL) pacc += o;
        if constexpr (DO_STATS) {
            float sx = o, sy = o * o;
#pragma unroll
            for (int off = 32; off; off >>= 1) { sx += __shfl_xor(sx, off); sy += __shfl_xor(sy, off); }
            if (lane == 0) { red[wv * 2] = sx; red[wv * 2 + 1] = sy; }
            __syncthreads();
            const float tsx = red[0] + red[2] + red[4] + red[6];
            const float tsy = red[1] + red[3] + red[5] + red[7];
            __syncthreads();
            if (c == 0) {
                const float mean = tsx * (1.f / 256.f);
                const float var  = tsy * (1.f / 256.f) - mean * mean;
                stats[(size_t)b * NTOK + n0 + t] = make_float2(mean, rsqrtf(var + 1e-5f));
            }
        }
    }
    if constexpr (DO_POOL) atomicAdd(&pooled[b * 512 + pool_off + c], pacc);
}

// ---------------------------------------------------------------------------
// bf16 transpose [b][tok][C] -> [b][C][tok]; LN variant reads fp32 + stats and
// applies LN on the fly. 64x64 tiles.
// ---------------------------------------------------------------------------
template<bool LN>
__launch_bounds__(256)
__global__ void tbf16_kernel(const float* __restrict__ inF, const u16* __restrict__ inB,
                             const float2* __restrict__ stats, const float* __restrict__ lnw,
                             const float* __restrict__ lnb, u16* __restrict__ outT) {
    const int b = blockIdx.z;
    const int tok0 = blockIdx.x * 64, c0 = blockIdx.y * 64;
    const int tid = threadIdx.x;
    __shared__ __align__(16) u16 tile[64][72];
    if constexpr (LN) {
        const float* ib = inF + (size_t)b * NTOK * C_;
#pragma unroll
        for (int q = 0; q < 4; q++) {
            const int chunk = q * 256 + tid;
            const int row = chunk >> 4, c4 = (chunk & 15) * 4;
            const float2 st = stats[(size_t)b * NTOK + tok0 + row];
            const float4 v = *(const float4*)&ib[(size_t)(tok0 + row) * C_ + c0 + c4];
            tile[c4 + 0][row] = f2bf((v.x - st.x) * st.y * lnw[c0 + c4 + 0] + lnb[c0 + c4 + 0]);
            tile[c4 + 1][row] = f2bf((v.y - st.x) * st.y * lnw[c0 + c4 + 1] + lnb[c0 + c4 + 1]);
            tile[c4 + 2][row] = f2bf((v.z - st.x) * st.y * lnw[c0 + c4 + 2] + lnb[c0 + c4 + 2]);
            tile[c4 + 3][row] = f2bf((v.w - st.x) * st.y * lnw[c0 + c4 + 3] + lnb[c0 + c4 + 3]);
        }
    } else {
        const u16* ib = inB + (size_t)b * NTOK * C_;
#pragma unroll
        for (int q = 0; q < 2; q++) {
            const int chunk = q * 256 + tid;
            const int row = chunk >> 3, c8 = (chunk & 7) * 8;
            const uint4 u = *(const uint4*)&ib[(size_t)(tok0 + row) * C_ + c0 + c8];
            tile[c8 + 0][row] = (u16)(u.x & 0xffffu); tile[c8 + 1][row] = (u16)(u.x >> 16);
            tile[c8 + 2][row] = (u16)(u.y & 0xffffu); tile[c8 + 3][row] = (u16)(u.y >> 16);
            tile[c8 + 4][row] = (u16)(u.z & 0xffffu); tile[c8 + 5][row] = (u16)(u.z >> 16);
            tile[c8 + 6][row] = (u16)(u.w & 0xffffu); tile[c8 + 7][row] = (u16)(u.w >> 16);
        }
    }
    __syncthreads();
    const int cr = tid >> 2, tch = (tid & 3) * 16;
    u16* op = outT + (size_t)b * C_ * NTOK + (size_t)(c0 + cr) * NTOK + tok0 + tch;
    *(uint4*)op       = *(const uint4*)&tile[cr][tch];
    *(uint4*)(op + 8) = *(const uint4*)&tile[cr][tch + 8];
}

// fp32 [K][N] -> bf16 transposed [N][K]
__launch_bounds__(256)
__global__ void wtrans_kernel(const float* __restrict__ in, u16* __restrict__ out, int K, int N) {
    const int n0 = blockIdx.x * 32, k0 = blockIdx.y * 32;
    const int tid = threadIdx.x;
    __shared__ float t[32][33];
#pragma unroll
    for (int q = 0; q < 4; q++) {
        const int chunk = q * 256 + tid;
        const int r = chunk >> 5, c = chunk & 31;
        t[r][c] = in[(size_t)(k0 + r) * N + n0 + c];
    }
    __syncthreads();
#pragma unroll
    for (int q = 0; q < 4; q++) {
        const int chunk = q * 256 + tid;
        const int r = chunk >> 5, c = chunk & 31;
        out[(size_t)(n0 + r) * K + k0 + c] = f2bf(t[c][r]);
    }
}

// ---------------------------------------------------------------------------
// S[b,hh,d,e] = scale * (Wk_hh^T @ G_b @ Wv_hh)[d,e].  grid 32 = (b*8+hh).
// ---------------------------------------------------------------------------
__launch_bounds__(256)
__global__ void sfromg_kernel(const float* __restrict__ G, const float* __restrict__ kv_w,
                              float* __restrict__ SM) {
    const int b = blockIdx.x >> 3, hh = blockIdx.x & 7;
    const int tid = threadIdx.x;
    __shared__ float Tl[256][33];
    __shared__ float Wvl[32][33];
    float acc[32];
#pragma unroll
    for (int e = 0; e < 32; e++) acc[e] = 0.f;
    const float* Gb = G + (size_t)b * 65536;
    for (int c0 = 0; c0 < 256; c0 += 32) {
#pragma unroll
        for (int q = 0; q < 8; q++) {
            const int idx = q * 256 + tid;
            const int r = idx >> 3, c4 = (idx & 7) * 4;
            *(float4*)&Tl[r][c4] = *(const float4*)&Gb[(size_t)r * 256 + c0 + c4];
        }
        {
            const int cc = tid >> 3, e4 = (tid & 7) * 4;
            *(float4*)&Wvl[cc][e4] = *(const float4*)&kv_w[(size_t)(c0 + cc) * 512 + 256 + hh * 32 + e4];
        }
        __syncthreads();
#pragma unroll 4
        for (int cc = 0; cc < 32; cc++) {
            const float g = Tl[tid][cc];
#pragma unroll
            for (int e = 0; e < 32; e++) acc[e] += g * Wvl[cc][e];
        }
        __syncthreads();
    }
#pragma unroll
    for (int e = 0; e < 32; e++) Tl[tid][e] = acc[e];
    __syncthreads();
    const int e = tid & 31, d0 = (tid >> 5) * 4;
    float s[4] = {0.f, 0.f, 0.f, 0.f};
    for (int r = 0; r < 256; r++) {
        const float t = Tl[r][e];
#pragma unroll
        for (int i = 0; i < 4; i++) s[i] += kv_w[(size_t)r * 512 + hh * 32 + d0 + i] * t;
    }
#pragma unroll
    for (int i = 0; i < 4; i++)
        SM[((size_t)(b * 8 + hh) * 32 + d0 + i) * 32 + e] = s[i] * 0.17677669529663687f;
}

__launch_bounds__(256)
__global__ void softmax32_kernel(float* __restrict__ Sm) {
    const int row = blockIdx.x * 8 + (threadIdx.x >> 5);
    const int e = threadIdx.x & 31;
    float v = Sm[row * 32 + e];
    float m = v;
#pragma unroll
    for (int off = 16; off; off >>= 1) m = fmaxf(m, __shfl_xor(m, off, 32));
    const float ex = expf(v - m);
    float s = ex;
#pragma unroll
    for (int off = 16; off; off >>= 1) s += __shfl_xor(s, off, 32);
    Sm[row * 32 + e] = ex / s;
}

// T1[b][i, hh*32+d] = sum_e q_w[i, hh*32+e] * A[b,hh,d,e].  grid 32.
__launch_bounds__(256)
__global__ void weff1_kernel(const float* __restrict__ q_w, const float* __restrict__ SM,
                             float* __restrict__ T1) {
    const int b = blockIdx.x >> 3, hh = blockIdx.x & 7;
    const int tid = threadIdx.x;
    __shared__ float A[32][33];
    {
        const int d = tid >> 3, e4 = (tid & 7) * 4;
        *(float4*)&A[d][e4] = *(const float4*)&SM[((size_t)(b * 8 + hh) * 32 + d) * 32 + e4];
    }
    __syncthreads();
    float qr[32];
#pragma unroll
    for (int e4 = 0; e4 < 8; e4++)
        *(float4*)&qr[e4 * 4] = *(const float4*)&q_w[(size_t)tid * 256 + hh * 32 + e4 * 4];
    float o[32];
#pragma unroll 4
    for (int d = 0; d < 32; d++) {
        float s = 0.f;
#pragma unroll
        for (int e = 0; e < 32; e++) s += qr[e] * A[d][e];
        o[d] = s;
    }
#pragma unroll
    for (int d4 = 0; d4 < 8; d4++)
        *(float4*)&T1[(size_t)b * 65536 + (size_t)tid * 256 + hh * 32 + d4 * 4] = *(float4*)&o[d4 * 4];
}

// WTb[b][n][k] (bf16) = (T1[b] @ proj_w)^T.  grid (4,4,B), 64x64 tile.
__launch_bounds__(256)
__global__ void weff2_kernel(const float* __restrict__ T1, const float* __restrict__ pw,
                             u16* __restrict__ WTb) {
    const int b = blockIdx.z;
    const int i0 = blockIdx.y * 64, j0 = blockIdx.x * 64;
    __shared__ float As2[16][64];
    __shared__ float Bs2[16][64];
    const int tid = threadIdx.x;
    const int tx = tid & 15, ty = tid >> 4;
    float acc[4][4];
#pragma unroll
    for (int i = 0; i < 4; i++)
#pragma unroll
        for (int j = 0; j < 4; j++) acc[i][j] = 0.f;
    const int ar = tid >> 2, ak4 = (tid & 3) * 4;
    const int bk = tid >> 4, bj4 = (tid & 15) * 4;
    for (int k0 = 0; k0 < 256; k0 += 16) {
        float4 av = *(const float4*)&T1[(size_t)b * 65536 + (size_t)(i0 + ar) * 256 + k0 + ak4];
        As2[ak4 + 0][ar] = av.x; As2[ak4 + 1][ar] = av.y;
        As2[ak4 + 2][ar] = av.z; As2[ak4 + 3][ar] = av.w;
        *(float4*)&Bs2[bk][bj4] = *(const float4*)&pw[(size_t)(k0 + bk) * 256 + j0 + bj4];
        __syncthreads();
#pragma unroll
        for (int kk = 0; kk < 16; kk++) {
            float a[4], c4[4];
            *(float4*)&a[0]  = *(const float4*)&As2[kk][ty * 4];
            *(float4*)&c4[0] = *(const float4*)&Bs2[kk][tx * 4];
#pragma unroll
            for (int i = 0; i < 4; i++)
#pragma unroll
                for (int j = 0; j < 4; j++) acc[i][j] += a[i] * c4[j];
        }
        __syncthreads();
    }
#pragma unroll
    for (int i = 0; i < 4; i++)
#pragma unroll
        for (int j = 0; j < 4; j++)
            WTb[(size_t)b * 65536 + (size_t)(j0 + tx * 4 + j) * 256 + i0 + ty * 4 + i] =
                f2bf(acc[i][j]);
}

// channel-interaction tiny MLP
__launch_bounds__(256)
__global__ void ci_kernel(const float* __restrict__ pooled, const float* __restrict__ w1,
                          const float* __restrict__ b1, const float* __restrict__ w2,
                          const float* __restrict__ b2, float* __restrict__ g) {
    const int b = blockIdx.x, t = threadIdx.x;
    __shared__ float pl[512];
    __shared__ float hid[256];
    pl[t]       = pooled[b * 512 + t]       * (1.f / NTOK);
    pl[t + 256] = pooled[b * 512 + 256 + t] * (1.f / NTOK);
    __syncthreads();
    float h = b1[t];
    for (int k = 0; k < 512; k++) h += pl[k] * w1[k * 256 + t];
    hid[t] = gelu_exact(h);
    __syncthreads();
    float g0 = b2[t], g1 = b2[t + 256];
    for (int k = 0; k < 256; k++) {
        const float hv = hid[k];
        g0 += hv * w2[k * 512 + t];
        g1 += hv * w2[k * 512 + 256 + t];
    }
    g[b * 512 + t]       = 1.f / (1.f + expf(-g0));
    g[b * 512 + 256 + t] = 1.f / (1.f + expf(-g1));
}

// ft = s_x*y2 + s_y*x2 (fp32) + LN2(ft) as bf16
__launch_bounds__(256)
__global__ void fcomb_kernel(const float* __restrict__ g, const float* __restrict__ x2,
                             const float* __restrict__ y2, const float* __restrict__ lnw,
                             const float* __restrict__ lnb, float* __restrict__ ft,
                             u16* __restrict__ ftl) {
    const int b = blockIdx.y;
    const int n0 = blockIdx.x * 16;
    const int c = threadIdx.x;
    const float sx = g[b * 512 + c];
    const float sy = g[b * 512 + 256 + c];
    const float lw = lnw[c], lb = lnb[c];
    const size_t base = ((size_t)b * NTOK + n0) * C_ + c;
    __shared__ float red[8];
    const int lane = c & 63, wv = c >> 6;
    for (int t = 0; t < 16; t++) {
        const size_t idx = base + (size_t)t * C_;
        const float f = sx * y2[idx] + sy * x2[idx];
        ft[idx] = f;
        float vx = f, vy = f * f;
#pragma unroll
        for (int off = 32; off; off >>= 1) { vx += __shfl_xor(vx, off); vy += __shfl_xor(vy, off); }
        if (lane == 0) { red[wv * 2] = vx; red[wv * 2 + 1] = vy; }
        __syncthreads();
        const float tsx = red[0] + red[2] + red[4] + red[6];
        const float tsy = red[1] + red[3] + red[5] + red[7];
        __syncthreads();
        const float mean = tsx * (1.f / 256.f);
        const float var  = tsy * (1.f / 256.f) - mean * mean;
        ftl[idx] = f2bf((f - mean) * rsqrtf(var + 1e-5f) * lw + lb);
    }
}

// out[b][c][n] = in[b][n][c]   (fp32)
__launch_bounds__(256)
__global__ void transpose_kernel(const float* __restrict__ in, float* __restrict__ out) {
    __shared__ float tile[32][33];
    const int b = blockIdx.z;
    const int n0 = blockIdx.x * 32, c0 = blockIdx.y * 32;
    const int tx = threadIdx.x & 31, ty = threadIdx.x >> 5;
    const float* ip = in + (size_t)b * NTOK * C_;
#pragma unroll
    for (int i = 0; i < 32; i += 8)
        tile[ty + i][tx] = ip[(size_t)(n0 + ty + i) * C_ + c0 + tx];
    __syncthreads();
    float* op = out + (size_t)b * C_ * NTOK;
#pragma unroll
    for (int i = 0; i < 32; i += 8)
        op[(size_t)(c0 + ty + i) * NTOK + n0 + tx] = tile[tx][ty + i];
}

// ---------------------------------------------------------------------------
extern "C" void kernel_launch(void* const* d_in, const int* in_sizes, int n_in,
                              void* d_out, int out_size, void* d_ws, size_t ws_size,
                              hipStream_t stream) {
    const float* x        = (const float*)d_in[0];
    const float* y        = (const float*)d_in[1];
    const float* cpex0_w  = (const float*)d_in[2];
    const float* cpex0_b  = (const float*)d_in[3];
    const float* cpey0_w  = (const float*)d_in[4];
    const float* cpey0_b  = (const float*)d_in[5];
    const float* cpex1_w  = (const float*)d_in[6];
    const float* cpex1_b  = (const float*)d_in[7];
    const float* cpey1_w  = (const float*)d_in[8];
    const float* cpey1_b  = (const float*)d_in[9];
    const float* ln1x_w   = (const float*)d_in[10];
    const float* ln1x_b   = (const float*)d_in[11];
    const float* ln1y_w   = (const float*)d_in[12];
    const float* ln1y_b   = (const float*)d_in[13];
    const float* ln2_w    = (const float*)d_in[14];
    const float* ln2_b    = (const float*)d_in[15];
    const float* attnx_kv = (const float*)d_in[16];
    const float* attnx_q  = (const float*)d_in[17];
    const float* attnx_pw = (const float*)d_in[18];
    const float* attnx_pb = (const float*)d_in[19];
    const float* attny_kv = (const float*)d_in[20];
    const float* attny_q  = (const float*)d_in[21];
    const float* attny_pw = (const float*)d_in[22];
    const float* attny_pb = (const float*)d_in[23];
    const float* ci_w1    = (const float*)d_in[24];
    const float* ci_b1    = (const float*)d_in[25];
    const float* ci_w2    = (const float*)d_in[26];
    const float* ci_b2    = (const float*)d_in[27];
    const float* fc1_b    = (const float*)d_in[29];
    const float* fc1_w    = (const float*)d_in[28];
    const float* fc2_w    = (const float*)d_in[30];
    const float* fc2_b    = (const float*)d_in[31];
    (void)in_sizes; (void)n_in; (void)out_size; (void)ws_size;

    const size_t S = (size_t)M_ * C_;         // 16,777,216 floats (64 MB)
    float* ws = (float*)d_ws;
    float2* STX   = (float2*)(ws + 0);        // [65536] float2
    float2* STY   = (float2*)(ws + 131072);
    float*  GRAM  = ws + 262144;              // 262144 fl (1 MB)
    float*  SM    = ws + 524288;              // 32768
    float*  T1    = ws + 557056;              // 262144
    u16*    WTB   = (u16*)(ws + 819200);      // 4*65536 u16
    u16*    FC1WT = (u16*)(ws + 950272);      // 262144 u16 [1024][256]
    u16*    FC2WT = (u16*)(ws + 1081344);     // 262144 u16 [256][1024]
    float*  PL    = ws + 1212416;             // 2048
    float*  GT    = ws + 1214464;             // 2048
    float*  W0  = ws + 2097152;               // S: xpe -> Xnew(in-place) -> y2
    float*  W1  = W0 + S;                     // S: ype -> Ynew(in-place) -> ft -> Fout(in-place)
    float*  W2  = W1 + S;                     // S as two bf16 halves
    u16*    W2a = (u16*)W2;                   // S/2 fl: Ylt -> Curxbt -> ftl
    u16*    W2b = (u16*)(W2 + S / 2);         // S/2 fl: Curxb
    float*  OUT = (float*)d_out;              // x2 -> Hid(bf16) -> final output
    u16*    HID = (u16*)d_out;

    const dim3 blk(256);
    const dim3 g_dw(NTOK / 16, B_);
    const dim3 g_tb(NTOK / 64, C_ / 64, B_);
    const size_t SB = 4194304;                // per-batch activation stride (elements)

    // 0) weight prep (bf16 transposed)
    wtrans_kernel<<<dim3(32, 8), blk, 0, stream>>>(fc1_w, FC1WT, 256, 1024);
    wtrans_kernel<<<dim3(8, 32), blk, 0, stream>>>(fc2_w, FC2WT, 1024, 256);

    // 1) dwconv PE #1 + LN stats
    dwconv_pe_kernel<true, false><<<g_dw, blk, 0, stream>>>(x, cpex0_w, cpex0_b, W0, STX, nullptr, 0);
    dwconv_pe_kernel<true, false><<<g_dw, blk, 0, stream>>>(y, cpey0_w, cpey0_b, W1, STY, nullptr, 0);

    // 2) XCA_x: Ylt = LN(ype)^T bf16; Gram; S; softmax; effective W
    tbf16_kernel<true><<<g_tb, blk, 0, stream>>>(W1, nullptr, STY, ln1y_w, ln1y_b, W2a);
    hipMemsetAsync(GRAM, 0, 262144 * sizeof(float), stream);
    gemm_mfma<false, false, 0, false, false, false, true><<<dim3(2, 2, 64), blk, 0, stream>>>(
        W2a, nullptr, nullptr, nullptr, nullptr, W2a, nullptr, nullptr, GRAM, nullptr,
        NTOK, NTOK, NTOK, 256, 16, SB, SB, 65536, 0);
    sfromg_kernel<<<dim3(32), blk, 0, stream>>>(GRAM, attnx_kv, SM);
    softmax32_kernel<<<dim3(128), blk, 0, stream>>>(SM);
    weff1_kernel<<<dim3(32), blk, 0, stream>>>(attnx_q, SM, T1);
    weff2_kernel<<<dim3(4, 4, B_), blk, 0, stream>>>(T1, attnx_pw, WTB);
    // apply-x (in-place): W0 = xpe + LN(xpe)@WT + pb; Curxb (pre-residual) bf16
    gemm_mfma<true, true, 0, true, true, true, false><<<dim3(2, 128, B_), blk, 0, stream>>>(
        nullptr, W0, STX, ln1x_w, ln1x_b, WTB, attnx_pb, W0, W0, W2b,
        256, 256, 256, 256, 1, SB, 65536, SB, SB);

    // 3) XCA_y: Curxbt; Gram; effective W; apply-y (in-place on W1)
    tbf16_kernel<false><<<g_tb, blk, 0, stream>>>(nullptr, W2b, nullptr, nullptr, nullptr, W2a);
    hipMemsetAsync(GRAM, 0, 262144 * sizeof(float), stream);
    gemm_mfma<false, false, 0, false, false, false, true><<<dim3(2, 2, 64), blk, 0, stream>>>(
        W2a, nullptr, nullptr, nullptr, nullptr, W2a, nullptr, nullptr, GRAM, nullptr,
        NTOK, NTOK, NTOK, 256, 16, SB, SB, 65536, 0);
    sfromg_kernel<<<dim3(32), blk, 0, stream>>>(GRAM, attny_kv, SM);
    softmax32_kernel<<<dim3(128), blk, 0, stream>>>(SM);
    weff1_kernel<<<dim3(32), blk, 0, stream>>>(attny_q, SM, T1);
    weff2_kernel<<<dim3(4, 4, B_), blk, 0, stream>>>(T1, attny_pw, WTB);
    gemm_mfma<true, true, 0, true, true, false, false><<<dim3(2, 128, B_), blk, 0, stream>>>(
        nullptr, W1, STY, ln1y_w, ln1y_b, WTB, attny_pb, W1, W1, nullptr,
        256, 256, 256, 256, 1, SB, 65536, SB, SB);

    // 4) dwconv PE #2 + pooling:  Xnew(W0)->x2(OUT),  Ynew(W1)->y2(W0)
    hipMemsetAsync(PL, 0, 2048 * sizeof(float), stream);
    dwconv_pe_kernel<false, true><<<g_dw, blk, 0, stream>>>(W0, cpex1_w, cpex1_b, OUT, nullptr, PL, 0);
    dwconv_pe_kernel<false, true><<<g_dw, blk, 0, stream>>>(W1, cpey1_w, cpey1_b, W0, nullptr, PL, 256);

    // 5) gates; ft(W1 fp32) + LN2 bf16 (W2a)
    ci_kernel<<<dim3(B_), blk, 0, stream>>>(PL, ci_w1, ci_b1, ci_w2, ci_b2, GT);
    fcomb_kernel<<<g_dw, blk, 0, stream>>>(GT, OUT, W0, ln2_w, ln2_b, W1, W2a);

    // 6) MLP split over hidden halves; Hid bf16 in d_out; Fout in-place in W1
    for (int h = 0; h < 2; h++) {
        gemm_mfma<false, true, 1, false, false, true, false><<<dim3(4, 512, 1), blk, 0, stream>>>(
            W2a, nullptr, nullptr, nullptr, nullptr, FC1WT + h * 512 * 256, fc1_b + h * 512,
            nullptr, nullptr, HID, 256, 256, 256, 512, 1, 0, 0, 0, 0);
        if (h == 0)
            gemm_mfma<false, true, 0, true, true, false, false><<<dim3(2, 512, 1), blk, 0, stream>>>(
                HID, nullptr, nullptr, nullptr, nullptr, FC2WT, fc2_b, W1, W1, nullptr,
                512, 512, 1024, 256, 1, 0, 0, 0, 0);
        else
            gemm_mfma<false, false, 0, true, true, false, false><<<dim3(2, 512, 1), blk, 0, stream>>>(
                HID, nullptr, nullptr, nullptr, nullptr, FC2WT + 512, nullptr, W1, W1, nullptr,
                512, 512, 1024, 256, 1, 0, 0, 0, 0);
    }

    // 7) (B,N,C) -> (B,C,H,W)
    transpose_kernel<<<dim3(NTOK / 32, C_ / 32, B_), blk, 0, stream>>>(W1, OUT);
}